// Round 5
// baseline (115.266 us; speedup 1.0000x reference)
//
#include <hip/hip_runtime.h>

// Causal linear attention (ELU+1), B=2 S=2048 H=16 D=64, chunk C=128.
// K1 prep_state: stage k,v -> bf16 exports + per-chunk state (bf16) via MFMA;
//                last-finishing block per bh scans that bh's states (ticket).
// K3 lin_attn_out: global_load_lds staging, q->regs, MFMA QK^T / W.V / Q.S0.

#define BB 2
#define SS 2048
#define HH 16
#define DD 64
#define CC 128
#define NC (SS / CC)           // 16
#define BH (BB * HH)           // 32
#define NCHUNK (BH * NC)       // 512

#define ST_STRIDE 8448LL       // 4096 bf16 state + 64 fp32 kz
#define WS_KB (512LL * ST_STRIDE)           // kbg
#define WS_VT (WS_KB + 512LL * 16384)       // vtg
#define WS_S0 (WS_VT + 512LL * 16384)       // s0g bf16 swizzled
#define WS_KZ (WS_S0 + 512LL * 8192)        // kzg fp32 prefix
#define WS_TK (WS_KZ + 512LL * 256)         // tickets (32 ints)

typedef __attribute__((ext_vector_type(8))) short bf16x8;
typedef __attribute__((ext_vector_type(4))) float f32x4;

__device__ __forceinline__ float phi(float x) {
    return x > 0.f ? x + 1.f : __expf(x);
}
__device__ __forceinline__ unsigned short f2bf(float x) {
    unsigned int u = __float_as_uint(x);
    u += 0x7fffu + ((u >> 16) & 1u);
    return (unsigned short)(u >> 16);
}
__device__ __forceinline__ float bf2f(unsigned short b) {
    return __uint_as_float(((unsigned int)b) << 16);
}
__device__ __forceinline__ void gload16(const void* g, void* lds) {
    __builtin_amdgcn_global_load_lds(
        (const __attribute__((address_space(1))) unsigned int*)g,
        (__attribute__((address_space(3))) unsigned int*)lds, 16, 0, 0);
}

// ---------------- Kernel 1: prep + state + (last block per bh) scan ----------------
__global__ __launch_bounds__(256, 2)
void prep_state(const float* __restrict__ qk, const float* __restrict__ v,
                char* __restrict__ st, unsigned short* __restrict__ kbg,
                unsigned short* __restrict__ vtg, unsigned short* __restrict__ s0g,
                float* __restrict__ kzg, int* __restrict__ tickets) {
    __shared__ unsigned short Kt[DD][136];   // [d][s] phi(k)
    __shared__ unsigned short Vt[DD][136];   // [e][s] v
    __shared__ int lastflag;

    const int tid = threadIdx.x, blk = blockIdx.x;
    const int bh = blk / NC, c = blk % NC, b = bh / HH, h = bh % HH;
    const int s0 = c * CC;
    const int lr = tid >> 4, lc = (tid & 15) * 4;
    char* kbc = (char*)kbg + (size_t)blk * 16384;

    #pragma unroll
    for (int it = 0; it < 8; ++it) {
        int row = it * 16 + lr;
        size_t ka = ((size_t)((b * SS + s0 + row) * 2 + 1)) * (HH * DD) + h * DD + lc;
        float4 kv = *(const float4*)(qk + ka);
        ushort4 kq = make_ushort4(f2bf(phi(kv.x)), f2bf(phi(kv.y)),
                                  f2bf(phi(kv.z)), f2bf(phi(kv.w)));
        *(ushort4*)(kbc + row * 128 + ((lc * 2) ^ ((row & 7) << 4))) = kq;
        Kt[lc + 0][row] = kq.x; Kt[lc + 1][row] = kq.y;
        Kt[lc + 2][row] = kq.z; Kt[lc + 3][row] = kq.w;
        size_t va = ((size_t)((b * SS + s0 + row) * HH + h)) * DD + lc;
        float4 vv = *(const float4*)(v + va);
        Vt[lc + 0][row] = f2bf(vv.x); Vt[lc + 1][row] = f2bf(vv.y);
        Vt[lc + 2][row] = f2bf(vv.z); Vt[lc + 3][row] = f2bf(vv.w);
    }
    __syncthreads();

    // export V^T (swizzled 256B rows)
    {
        char* vtc = (char*)vtg + (size_t)blk * 16384;
        int e = tid >> 2, sq = (tid & 3) * 32;
        #pragma unroll
        for (int k8 = 0; k8 < 4; ++k8) {
            int s = sq + k8 * 8;
            bf16x8 val = *(const bf16x8*)&Vt[e][s];
            *(bf16x8*)(vtc + e * 256 + ((s * 2) ^ ((e & 7) << 4))) = val;
        }
    }

    // MFMA: state[e][d] = sum_s V[s][e] K[s][d]; kz[d] (wave 0 only)
    const int w = tid >> 6, lane = tid & 63, g = lane >> 4, ln = lane & 15;
    {
        bf16x8 av[4];
        #pragma unroll
        for (int ks = 0; ks < 4; ++ks)
            av[ks] = *(const bf16x8*)&Vt[w * 16 + ln][ks * 32 + g * 8];
        bf16x8 ones;
        #pragma unroll
        for (int j = 0; j < 8; ++j) ones[j] = (short)0x3F80;

        char* stc = st + (size_t)blk * ST_STRIDE;
        #pragma unroll
        for (int n = 0; n < 4; ++n) {
            f32x4 a = {0.f, 0.f, 0.f, 0.f}, kz4 = {0.f, 0.f, 0.f, 0.f};
            #pragma unroll
            for (int ks = 0; ks < 4; ++ks) {
                bf16x8 bk = *(const bf16x8*)&Kt[n * 16 + ln][ks * 32 + g * 8];
                a = __builtin_amdgcn_mfma_f32_16x16x32_bf16(av[ks], bk, a, 0, 0, 0);
                if (w == 0)
                    kz4 = __builtin_amdgcn_mfma_f32_16x16x32_bf16(ones, bk, kz4, 0, 0, 0);
            }
            #pragma unroll
            for (int r = 0; r < 4; ++r)
                *(unsigned short*)(stc + (((w * 16 + g * 4 + r) * 64) + n * 16 + ln) * 2)
                    = f2bf(a[r]);
            if (w == 0 && g == 0)
                *(float*)(stc + 8192 + (n * 16 + ln) * 4) = kz4[0];
        }
    }

    // ---- ticket: last block of this bh scans the bh ----
    __threadfence();
    __syncthreads();
    if (tid == 0)
        lastflag = (atomicAdd(&tickets[bh], 1) == NC - 1) ? 1 : 0;
    __syncthreads();
    if (!lastflag) return;
    __threadfence();

    const char* stb = st + (size_t)(bh * NC) * ST_STRIDE;
    char* s0b = (char*)s0g + (size_t)(bh * NC) * 8192;
    float* kzb = kzg + (size_t)(bh * NC) * 64;
    #pragma unroll
    for (int it = 0; it < 4; ++it) {
        int i = it * 256 + tid;          // 0..1023 ushort4 items
        int i4 = i * 4, e = i4 >> 6, d = i4 & 63;
        const char* src = stb + i * 8;
        char* dst = s0b + e * 128 + ((d * 2) ^ ((e & 7) << 4));
        float4 run = {0.f, 0.f, 0.f, 0.f};
        #pragma unroll
        for (int c2 = 0; c2 < NC; ++c2) {
            *(ushort4*)(dst + (size_t)c2 * 8192) =
                make_ushort4(f2bf(run.x), f2bf(run.y), f2bf(run.z), f2bf(run.w));
            ushort4 x = *(const ushort4*)(src + (size_t)c2 * ST_STRIDE);
            run.x += bf2f(x.x); run.y += bf2f(x.y);
            run.z += bf2f(x.z); run.w += bf2f(x.w);
        }
    }
    if (tid < 16) {
        int j = tid * 4;
        const char* src = stb + 8192 + j * 4;
        float* dst = kzb + j;
        float4 run = {0.f, 0.f, 0.f, 0.f};
        #pragma unroll
        for (int c2 = 0; c2 < NC; ++c2) {
            *(float4*)(dst + (size_t)c2 * 64) = run;
            float4 x = *(const float4*)(src + (size_t)c2 * ST_STRIDE);
            run.x += x.x; run.y += x.y; run.z += x.z; run.w += x.w;
        }
    }
}

// ---------------- Kernel 3: per-chunk output via MFMA ----------------
__global__ __launch_bounds__(256, 2)
void lin_attn_out(const float* __restrict__ qk,
                  const unsigned short* __restrict__ kbg,
                  const unsigned short* __restrict__ vtg,
                  const unsigned short* __restrict__ s0g,
                  const float* __restrict__ kzg,
                  float* __restrict__ out) {
    __shared__ __align__(16) char KbL[16384];            // [s][d] swizzled
    __shared__ __align__(16) char VtL[16384];            // [e][s] swizzled
    __shared__ __align__(16) char S0L[8192];             // [e][d] swizzled
    __shared__ float kzl[DD];
    __shared__ __align__(16) unsigned short Wl[4][32][40];
    __shared__ float nul[4][32];

    const int tid = threadIdx.x, blk = blockIdx.x;
    const int bh = blk / NC, c = blk % NC, b = bh / HH, h = bh % HH;
    const int s0 = c * CC;
    const int w = tid >> 6, lane = tid & 63, g = lane >> 4, ln = lane & 15;
    const int wband = (blk & 1) ? (3 - w) : w;   // SIMD load balance across 2 blocks/CU

    // async stage K, V^T, S0
    {
        const char* kbs = (const char*)kbg + (size_t)blk * 16384;
        const char* vts = (const char*)vtg + (size_t)blk * 16384;
        const char* s0s = (const char*)s0g + (size_t)blk * 8192;
        #pragma unroll
        for (int i = 0; i < 4; ++i) {
            gload16(kbs + w * 4096 + i * 1024 + lane * 16, KbL + w * 4096 + i * 1024);
            gload16(vts + w * 4096 + i * 1024 + lane * 16, VtL + w * 4096 + i * 1024);
        }
        #pragma unroll
        for (int i = 0; i < 2; ++i)
            gload16(s0s + w * 2048 + i * 1024 + lane * 16, S0L + w * 2048 + i * 1024);
        if (tid < DD) kzl[tid] = kzg[(size_t)blk * 64 + tid];
    }

    // q -> registers (phi + bf16)
    bf16x8 aq[2][2];
    #pragma unroll
    for (int m = 0; m < 2; ++m) {
        int tg = s0 + wband * 32 + m * 16 + ln;
        const float* qrow = qk + ((size_t)((b * SS + tg) * 2)) * (HH * DD) + h * DD;
        #pragma unroll
        for (int kb2 = 0; kb2 < 2; ++kb2) {
            float4 x0 = *(const float4*)(qrow + kb2 * 32 + g * 8);
            float4 x1 = *(const float4*)(qrow + kb2 * 32 + g * 8 + 4);
            bf16x8 f;
            f[0] = (short)f2bf(phi(x0.x)); f[1] = (short)f2bf(phi(x0.y));
            f[2] = (short)f2bf(phi(x0.z)); f[3] = (short)f2bf(phi(x0.w));
            f[4] = (short)f2bf(phi(x1.x)); f[5] = (short)f2bf(phi(x1.y));
            f[6] = (short)f2bf(phi(x1.z)); f[7] = (short)f2bf(phi(x1.w));
            aq[m][kb2] = f;
        }
    }
    __syncthreads();

    f32x4 O[2][4];
    #pragma unroll
    for (int m = 0; m < 2; ++m)
        #pragma unroll
        for (int n = 0; n < 4; ++n) O[m][n] = (f32x4){0.f, 0.f, 0.f, 0.f};

    // inter-chunk: O += Q * S0
    #pragma unroll
    for (int n = 0; n < 4; ++n) {
        int e = n * 16 + ln;
        bf16x8 b0 = *(const bf16x8*)(S0L + e * 128 + ((g * 16) ^ ((e & 7) << 4)));
        bf16x8 b1 = *(const bf16x8*)(S0L + e * 128 + ((64 + g * 16) ^ ((e & 7) << 4)));
        #pragma unroll
        for (int m = 0; m < 2; ++m) {
            O[m][n] = __builtin_amdgcn_mfma_f32_16x16x32_bf16(aq[m][0], b0, O[m][n], 0, 0, 0);
            O[m][n] = __builtin_amdgcn_mfma_f32_16x16x32_bf16(aq[m][1], b1, O[m][n], 0, 0, 0);
        }
    }

    // nu base: q . kz
    float nuA[2] = {0.f, 0.f};
    #pragma unroll
    for (int kb2 = 0; kb2 < 2; ++kb2)
        #pragma unroll
        for (int j = 0; j < 8; ++j) {
            float kzv = kzl[kb2 * 32 + g * 8 + j];
            nuA[0] = fmaf(bf2f((unsigned short)aq[0][kb2][j]), kzv, nuA[0]);
            nuA[1] = fmaf(bf2f((unsigned short)aq[1][kb2][j]), kzv, nuA[1]);
        }

    // causal s-block loop over this wave's band
    for (int sblk = 0; sblk <= wband; ++sblk) {
        const bool diag = (sblk == wband);
        f32x4 Sc[2][2];
        #pragma unroll
        for (int m = 0; m < 2; ++m)
            #pragma unroll
            for (int ns = 0; ns < 2; ++ns) Sc[m][ns] = (f32x4){0.f, 0.f, 0.f, 0.f};

        #pragma unroll
        for (int ns = 0; ns < 2; ++ns) {
            int s = sblk * 32 + ns * 16 + ln;
            const char* srow = KbL + s * 128;
            bf16x8 bk0 = *(const bf16x8*)(srow + ((g * 16) ^ ((s & 7) << 4)));
            bf16x8 bk1 = *(const bf16x8*)(srow + ((64 + g * 16) ^ ((s & 7) << 4)));
            #pragma unroll
            for (int m = 0; m < 2; ++m) {
                Sc[m][ns] = __builtin_amdgcn_mfma_f32_16x16x32_bf16(aq[m][0], bk0, Sc[m][ns], 0, 0, 0);
                Sc[m][ns] = __builtin_amdgcn_mfma_f32_16x16x32_bf16(aq[m][1], bk1, Sc[m][ns], 0, 0, 0);
            }
        }

        // mask + bounce (f32 C-layout -> bf16 A-layout)
        #pragma unroll
        for (int m = 0; m < 2; ++m)
            #pragma unroll
            for (int ns = 0; ns < 2; ++ns)
                #pragma unroll
                for (int r = 0; r < 4; ++r) {
                    int t_loc = m * 16 + g * 4 + r;
                    int s_loc = ns * 16 + ln;
                    float val = Sc[m][ns][r];
                    if (diag && s_loc > t_loc) val = 0.f;
                    Wl[w][t_loc][s_loc] = f2bf(val);
                }
        asm volatile("s_waitcnt lgkmcnt(0)" ::: "memory");
        __builtin_amdgcn_sched_barrier(0);

        bf16x8 bv[4];
        #pragma unroll
        for (int n = 0; n < 4; ++n) {
            int e = n * 16 + ln;
            bv[n] = *(const bf16x8*)(VtL + e * 256 + ((sblk * 64 + g * 16) ^ ((e & 7) << 4)));
        }

        #pragma unroll
        for (int m = 0; m < 2; ++m) {
            bf16x8 pa = *(const bf16x8*)&Wl[w][m * 16 + ln][g * 8];
            float rs = 0.f;
            #pragma unroll
            for (int j = 0; j < 8; ++j) rs += bf2f((unsigned short)pa[j]);
            nuA[m] += rs;
            #pragma unroll
            for (int n = 0; n < 4; ++n)
                O[m][n] = __builtin_amdgcn_mfma_f32_16x16x32_bf16(pa, bv[n], O[m][n], 0, 0, 0);
        }
    }

    // nu reduce + normalize + store
    #pragma unroll
    for (int m = 0; m < 2; ++m) {
        float nt = nuA[m];
        nt += __shfl_xor(nt, 16);
        nt += __shfl_xor(nt, 32);
        if (g == 0) nul[w][m * 16 + ln] = nt;
    }
    asm volatile("s_waitcnt lgkmcnt(0)" ::: "memory");
    __builtin_amdgcn_sched_barrier(0);

    #pragma unroll
    for (int m = 0; m < 2; ++m) {
        float inv[4];
        #pragma unroll
        for (int r = 0; r < 4; ++r) inv[r] = 1.f / nul[w][m * 16 + g * 4 + r];
        #pragma unroll
        for (int n = 0; n < 4; ++n)
            #pragma unroll
            for (int r = 0; r < 4; ++r) {
                int t = wband * 32 + m * 16 + g * 4 + r;
                int e = n * 16 + ln;
                size_t oa = ((size_t)((b * SS + s0 + t) * HH + h)) * DD + e;
                out[oa] = O[m][n][r] * inv[r];
            }
    }
}

extern "C" void kernel_launch(void* const* d_in, const int* in_sizes, int n_in,
                              void* d_out, int out_size, void* d_ws, size_t ws_size,
                              hipStream_t stream) {
    const float* qk = (const float*)d_in[0];
    const float* v  = (const float*)d_in[1];
    float* outp = (float*)d_out;

    char* st = (char*)d_ws;
    unsigned short* kbg = (unsigned short*)((char*)d_ws + WS_KB);
    unsigned short* vtg = (unsigned short*)((char*)d_ws + WS_VT);
    unsigned short* s0g = (unsigned short*)((char*)d_ws + WS_S0);
    float* kzg = (float*)((char*)d_ws + WS_KZ);
    int* tickets = (int*)((char*)d_ws + WS_TK);

    hipMemsetAsync(tickets, 0, BH * sizeof(int), stream);
    prep_state<<<NCHUNK, 256, 0, stream>>>(qk, v, st, kbg, vtg, s0g, kzg, tickets);
    lin_attn_out<<<NCHUNK, 256, 0, stream>>>(qk, kbg, vtg, s0g, kzg, outp);
}

// Round 6
// 33.999 us; speedup vs baseline: 3.3903x; 3.3903x over previous
//
#include <hip/hip_runtime.h>

// Causal linear attention (ELU+1), B=2 S=2048 H=16 D=64, chunk C=128.
// K1 prep_state: stage k,v -> bf16 swizzled exports + per-chunk state (bf16) via MFMA.
// K2 chunk_scan: exclusive prefix over chunk states -> s0 bf16 swizzled + kz fp32.
// K3 lin_attn_out: global_load_lds staging, q->regs, MFMA QK^T / W.V / Q.S0.

#define BB 2
#define SS 2048
#define HH 16
#define DD 64
#define CC 128
#define NC (SS / CC)           // 16
#define BH (BB * HH)           // 32
#define NCHUNK (BH * NC)       // 512

#define ST_STRIDE 8448LL       // bytes: 4096 bf16 state + 64 fp32 kz
#define WS_KB (512LL * ST_STRIDE)           // kbg
#define WS_VT (WS_KB + 512LL * 16384)       // vtg
#define WS_S0 (WS_VT + 512LL * 16384)       // s0g bf16 swizzled
#define WS_KZ (WS_S0 + 512LL * 8192)        // kzg fp32 prefix

typedef __attribute__((ext_vector_type(8))) short bf16x8;
typedef __attribute__((ext_vector_type(4))) float f32x4;

__device__ __forceinline__ float phi(float x) {
    return x > 0.f ? x + 1.f : __expf(x);
}
__device__ __forceinline__ unsigned short f2bf(float x) {
    unsigned int u = __float_as_uint(x);
    u += 0x7fffu + ((u >> 16) & 1u);
    return (unsigned short)(u >> 16);
}
__device__ __forceinline__ float bf2f(unsigned short b) {
    return __uint_as_float(((unsigned int)b) << 16);
}
__device__ __forceinline__ void gload16(const void* g, void* lds) {
    __builtin_amdgcn_global_load_lds(
        (const __attribute__((address_space(1))) unsigned int*)g,
        (__attribute__((address_space(3))) unsigned int*)lds, 16, 0, 0);
}

// ---------------- Kernel 1: prep + per-chunk state ----------------
__global__ __launch_bounds__(256, 2)
void prep_state(const float* __restrict__ qk, const float* __restrict__ v,
                char* __restrict__ st, unsigned short* __restrict__ kbg,
                unsigned short* __restrict__ vtg) {
    __shared__ unsigned short Kt[DD][136];   // [d][s] phi(k)
    __shared__ unsigned short Vt[DD][136];   // [e][s] v

    const int tid = threadIdx.x, blk = blockIdx.x;
    const int bh = blk / NC, c = blk % NC, b = bh / HH, h = bh % HH;
    const int s0 = c * CC;
    const int lr = tid >> 4, lc = (tid & 15) * 4;
    char* kbc = (char*)kbg + (size_t)blk * 16384;

    #pragma unroll
    for (int it = 0; it < 8; ++it) {
        int row = it * 16 + lr;
        size_t ka = ((size_t)((b * SS + s0 + row) * 2 + 1)) * (HH * DD) + h * DD + lc;
        float4 kv = *(const float4*)(qk + ka);
        ushort4 kq = make_ushort4(f2bf(phi(kv.x)), f2bf(phi(kv.y)),
                                  f2bf(phi(kv.z)), f2bf(phi(kv.w)));
        *(ushort4*)(kbc + row * 128 + ((lc * 2) ^ ((row & 7) << 4))) = kq;
        Kt[lc + 0][row] = kq.x; Kt[lc + 1][row] = kq.y;
        Kt[lc + 2][row] = kq.z; Kt[lc + 3][row] = kq.w;
        size_t va = ((size_t)((b * SS + s0 + row) * HH + h)) * DD + lc;
        float4 vv = *(const float4*)(v + va);
        Vt[lc + 0][row] = f2bf(vv.x); Vt[lc + 1][row] = f2bf(vv.y);
        Vt[lc + 2][row] = f2bf(vv.z); Vt[lc + 3][row] = f2bf(vv.w);
    }
    __syncthreads();

    // export V^T (swizzled 256B rows)
    {
        char* vtc = (char*)vtg + (size_t)blk * 16384;
        int e = tid >> 2, sq = (tid & 3) * 32;
        #pragma unroll
        for (int k8 = 0; k8 < 4; ++k8) {
            int s = sq + k8 * 8;
            bf16x8 val = *(const bf16x8*)&Vt[e][s];
            *(bf16x8*)(vtc + e * 256 + ((s * 2) ^ ((e & 7) << 4))) = val;
        }
    }

    // MFMA: state[e][d] = sum_s V[s][e] K[s][d]; kz[d] via ones-A (wave 0)
    const int w = tid >> 6, lane = tid & 63, g = lane >> 4, ln = lane & 15;
    {
        bf16x8 av[4];
        #pragma unroll
        for (int ks = 0; ks < 4; ++ks)
            av[ks] = *(const bf16x8*)&Vt[w * 16 + ln][ks * 32 + g * 8];
        bf16x8 ones;
        #pragma unroll
        for (int j = 0; j < 8; ++j) ones[j] = (short)0x3F80;

        char* stc = st + (size_t)blk * ST_STRIDE;
        #pragma unroll
        for (int n = 0; n < 4; ++n) {
            f32x4 a = {0.f, 0.f, 0.f, 0.f}, kz4 = {0.f, 0.f, 0.f, 0.f};
            #pragma unroll
            for (int ks = 0; ks < 4; ++ks) {
                bf16x8 bk = *(const bf16x8*)&Kt[n * 16 + ln][ks * 32 + g * 8];
                a = __builtin_amdgcn_mfma_f32_16x16x32_bf16(av[ks], bk, a, 0, 0, 0);
                if (w == 0)
                    kz4 = __builtin_amdgcn_mfma_f32_16x16x32_bf16(ones, bk, kz4, 0, 0, 0);
            }
            #pragma unroll
            for (int r = 0; r < 4; ++r)
                *(unsigned short*)(stc + (((w * 16 + g * 4 + r) * 64) + n * 16 + ln) * 2)
                    = f2bf(a[r]);
            if (w == 0 && g == 0)
                *(float*)(stc + 8192 + (n * 16 + ln) * 4) = kz4[0];
        }
    }
}

// ---------------- Kernel 2: exclusive prefix over chunks ----------------
__global__ __launch_bounds__(256)
void chunk_scan(const char* __restrict__ st, unsigned short* __restrict__ s0g,
                float* __restrict__ kzg) {
    int flat = blockIdx.x * 256 + threadIdx.x;   // 130*256 = 33280 = 32*1040
    int bh = flat / 1040, i = flat % 1040;
    const char* stb = st + (size_t)(bh * NC) * ST_STRIDE;
    if (i < 1024) {
        int i4 = i * 4, e = i4 >> 6, d = i4 & 63;
        const char* src = stb + i * 8;
        char* dst = (char*)s0g + (size_t)(bh * NC) * 8192
                    + e * 128 + ((d * 2) ^ ((e & 7) << 4));
        float4 run = {0.f, 0.f, 0.f, 0.f};
        #pragma unroll
        for (int c2 = 0; c2 < NC; ++c2) {
            *(ushort4*)(dst + (size_t)c2 * 8192) =
                make_ushort4(f2bf(run.x), f2bf(run.y), f2bf(run.z), f2bf(run.w));
            ushort4 x = *(const ushort4*)(src + (size_t)c2 * ST_STRIDE);
            run.x += bf2f(x.x); run.y += bf2f(x.y);
            run.z += bf2f(x.z); run.w += bf2f(x.w);
        }
    } else {
        int j = (i - 1024) * 4;   // 0..60
        const char* src = stb + 8192 + j * 4;
        float* dst = kzg + (size_t)(bh * NC) * 64 + j;
        float4 run = {0.f, 0.f, 0.f, 0.f};
        #pragma unroll
        for (int c2 = 0; c2 < NC; ++c2) {
            *(float4*)(dst + (size_t)c2 * 64) = run;
            float4 x = *(const float4*)(src + (size_t)c2 * ST_STRIDE);
            run.x += x.x; run.y += x.y; run.z += x.z; run.w += x.w;
        }
    }
}

// ---------------- Kernel 3: per-chunk output via MFMA ----------------
__global__ __launch_bounds__(256, 2)
void lin_attn_out(const float* __restrict__ qk,
                  const unsigned short* __restrict__ kbg,
                  const unsigned short* __restrict__ vtg,
                  const unsigned short* __restrict__ s0g,
                  const float* __restrict__ kzg,
                  float* __restrict__ out) {
    __shared__ __align__(16) char KbL[16384];            // [s][d] swizzled
    __shared__ __align__(16) char VtL[16384];            // [e][s] swizzled
    __shared__ __align__(16) char S0L[8192];             // [e][d] swizzled
    __shared__ float kzl[DD];
    __shared__ __align__(16) unsigned short Wl[4][32][40];
    __shared__ float nul[4][32];

    const int tid = threadIdx.x, blk = blockIdx.x;
    const int bh = blk / NC, c = blk % NC, b = bh / HH, h = bh % HH;
    const int s0 = c * CC;
    const int w = tid >> 6, lane = tid & 63, g = lane >> 4, ln = lane & 15;
    const int wband = (blk & 1) ? (3 - w) : w;   // SIMD load balance across 2 blocks/CU

    // async stage K, V^T, S0
    {
        const char* kbs = (const char*)kbg + (size_t)blk * 16384;
        const char* vts = (const char*)vtg + (size_t)blk * 16384;
        const char* s0s = (const char*)s0g + (size_t)blk * 8192;
        #pragma unroll
        for (int i = 0; i < 4; ++i) {
            gload16(kbs + w * 4096 + i * 1024 + lane * 16, KbL + w * 4096 + i * 1024);
            gload16(vts + w * 4096 + i * 1024 + lane * 16, VtL + w * 4096 + i * 1024);
        }
        #pragma unroll
        for (int i = 0; i < 2; ++i)
            gload16(s0s + w * 2048 + i * 1024 + lane * 16, S0L + w * 2048 + i * 1024);
        if (tid < DD) kzl[tid] = kzg[(size_t)blk * 64 + tid];
    }

    // q -> registers (phi + bf16)
    bf16x8 aq[2][2];
    #pragma unroll
    for (int m = 0; m < 2; ++m) {
        int tg = s0 + wband * 32 + m * 16 + ln;
        const float* qrow = qk + ((size_t)((b * SS + tg) * 2)) * (HH * DD) + h * DD;
        #pragma unroll
        for (int kb2 = 0; kb2 < 2; ++kb2) {
            float4 x0 = *(const float4*)(qrow + kb2 * 32 + g * 8);
            float4 x1 = *(const float4*)(qrow + kb2 * 32 + g * 8 + 4);
            bf16x8 f;
            f[0] = (short)f2bf(phi(x0.x)); f[1] = (short)f2bf(phi(x0.y));
            f[2] = (short)f2bf(phi(x0.z)); f[3] = (short)f2bf(phi(x0.w));
            f[4] = (short)f2bf(phi(x1.x)); f[5] = (short)f2bf(phi(x1.y));
            f[6] = (short)f2bf(phi(x1.z)); f[7] = (short)f2bf(phi(x1.w));
            aq[m][kb2] = f;
        }
    }
    __syncthreads();

    f32x4 O[2][4];
    #pragma unroll
    for (int m = 0; m < 2; ++m)
        #pragma unroll
        for (int n = 0; n < 4; ++n) O[m][n] = (f32x4){0.f, 0.f, 0.f, 0.f};

    // inter-chunk: O += Q * S0
    #pragma unroll
    for (int n = 0; n < 4; ++n) {
        int e = n * 16 + ln;
        bf16x8 b0 = *(const bf16x8*)(S0L + e * 128 + ((g * 16) ^ ((e & 7) << 4)));
        bf16x8 b1 = *(const bf16x8*)(S0L + e * 128 + ((64 + g * 16) ^ ((e & 7) << 4)));
        #pragma unroll
        for (int m = 0; m < 2; ++m) {
            O[m][n] = __builtin_amdgcn_mfma_f32_16x16x32_bf16(aq[m][0], b0, O[m][n], 0, 0, 0);
            O[m][n] = __builtin_amdgcn_mfma_f32_16x16x32_bf16(aq[m][1], b1, O[m][n], 0, 0, 0);
        }
    }

    // nu base: q . kz
    float nuA[2] = {0.f, 0.f};
    #pragma unroll
    for (int kb2 = 0; kb2 < 2; ++kb2)
        #pragma unroll
        for (int j = 0; j < 8; ++j) {
            float kzv = kzl[kb2 * 32 + g * 8 + j];
            nuA[0] = fmaf(bf2f((unsigned short)aq[0][kb2][j]), kzv, nuA[0]);
            nuA[1] = fmaf(bf2f((unsigned short)aq[1][kb2][j]), kzv, nuA[1]);
        }

    // causal s-block loop over this wave's band
    for (int sblk = 0; sblk <= wband; ++sblk) {
        const bool diag = (sblk == wband);
        f32x4 Sc[2][2];
        #pragma unroll
        for (int m = 0; m < 2; ++m)
            #pragma unroll
            for (int ns = 0; ns < 2; ++ns) Sc[m][ns] = (f32x4){0.f, 0.f, 0.f, 0.f};

        #pragma unroll
        for (int ns = 0; ns < 2; ++ns) {
            int s = sblk * 32 + ns * 16 + ln;
            const char* srow = KbL + s * 128;
            bf16x8 bk0 = *(const bf16x8*)(srow + ((g * 16) ^ ((s & 7) << 4)));
            bf16x8 bk1 = *(const bf16x8*)(srow + ((64 + g * 16) ^ ((s & 7) << 4)));
            #pragma unroll
            for (int m = 0; m < 2; ++m) {
                Sc[m][ns] = __builtin_amdgcn_mfma_f32_16x16x32_bf16(aq[m][0], bk0, Sc[m][ns], 0, 0, 0);
                Sc[m][ns] = __builtin_amdgcn_mfma_f32_16x16x32_bf16(aq[m][1], bk1, Sc[m][ns], 0, 0, 0);
            }
        }

        // mask + bounce (f32 C-layout -> bf16 A-layout)
        #pragma unroll
        for (int m = 0; m < 2; ++m)
            #pragma unroll
            for (int ns = 0; ns < 2; ++ns)
                #pragma unroll
                for (int r = 0; r < 4; ++r) {
                    int t_loc = m * 16 + g * 4 + r;
                    int s_loc = ns * 16 + ln;
                    float val = Sc[m][ns][r];
                    if (diag && s_loc > t_loc) val = 0.f;
                    Wl[w][t_loc][s_loc] = f2bf(val);
                }
        asm volatile("s_waitcnt lgkmcnt(0)" ::: "memory");
        __builtin_amdgcn_sched_barrier(0);

        bf16x8 bv[4];
        #pragma unroll
        for (int n = 0; n < 4; ++n) {
            int e = n * 16 + ln;
            bv[n] = *(const bf16x8*)(VtL + e * 256 + ((sblk * 64 + g * 16) ^ ((e & 7) << 4)));
        }

        #pragma unroll
        for (int m = 0; m < 2; ++m) {
            bf16x8 pa = *(const bf16x8*)&Wl[w][m * 16 + ln][g * 8];
            float rs = 0.f;
            #pragma unroll
            for (int j = 0; j < 8; ++j) rs += bf2f((unsigned short)pa[j]);
            nuA[m] += rs;
            #pragma unroll
            for (int n = 0; n < 4; ++n)
                O[m][n] = __builtin_amdgcn_mfma_f32_16x16x32_bf16(pa, bv[n], O[m][n], 0, 0, 0);
        }
    }

    // nu reduce + normalize + store
    #pragma unroll
    for (int m = 0; m < 2; ++m) {
        float nt = nuA[m];
        nt += __shfl_xor(nt, 16);
        nt += __shfl_xor(nt, 32);
        if (g == 0) nul[w][m * 16 + ln] = nt;
    }
    asm volatile("s_waitcnt lgkmcnt(0)" ::: "memory");
    __builtin_amdgcn_sched_barrier(0);

    #pragma unroll
    for (int m = 0; m < 2; ++m) {
        float inv[4];
        #pragma unroll
        for (int r = 0; r < 4; ++r) inv[r] = 1.f / nul[w][m * 16 + g * 4 + r];
        #pragma unroll
        for (int n = 0; n < 4; ++n)
            #pragma unroll
            for (int r = 0; r < 4; ++r) {
                int t = wband * 32 + m * 16 + g * 4 + r;
                int e = n * 16 + ln;
                size_t oa = ((size_t)((b * SS + s0 + t) * HH + h)) * DD + e;
                out[oa] = O[m][n][r] * inv[r];
            }
    }
}

extern "C" void kernel_launch(void* const* d_in, const int* in_sizes, int n_in,
                              void* d_out, int out_size, void* d_ws, size_t ws_size,
                              hipStream_t stream) {
    const float* qk = (const float*)d_in[0];
    const float* v  = (const float*)d_in[1];
    float* outp = (float*)d_out;

    char* st = (char*)d_ws;
    unsigned short* kbg = (unsigned short*)((char*)d_ws + WS_KB);
    unsigned short* vtg = (unsigned short*)((char*)d_ws + WS_VT);
    unsigned short* s0g = (unsigned short*)((char*)d_ws + WS_S0);
    float* kzg = (float*)((char*)d_ws + WS_KZ);

    prep_state<<<NCHUNK, 256, 0, stream>>>(qk, v, st, kbg, vtg);
    chunk_scan<<<130, 256, 0, stream>>>(st, s0g, kzg);
    lin_attn_out<<<NCHUNK, 256, 0, stream>>>(qk, kbg, vtg, s0g, kzg, outp);
}